// Round 1
// baseline (1325.897 us; speedup 1.0000x reference)
//
#include <hip/hip_runtime.h>
#include <hip/hip_bf16.h>

// Problem constants (from reference)
#define IN_PER_SIDE   40960
#define IN_TOTAL      81920     // 2 * 40960
#define L1            512
#define L2            32
#define L3_           32
#define BATCH         4096
#define MAXIDX        128       // per-row index capacity (~60 used)

// clang-native vectors (HIP float4 is a class; builtins reject it)
typedef float        v4f __attribute__((ext_vector_type(4)));
typedef float        v8f __attribute__((ext_vector_type(8)));
typedef _Float16     v4h __attribute__((ext_vector_type(4)));
typedef _Float16     v8h __attribute__((ext_vector_type(8)));
typedef unsigned int v4u __attribute__((ext_vector_type(4)));

// WT stored as fp16: 81920 * 512 * 2 B = 83.9 MB (halves write + gather traffic;
// |W_in| <= 0.0035 so fp16 abs err ~1.7e-6/entry -> output err ~1e-5, thr 4.6e-4)
#define WT_BYTES ((size_t)IN_TOTAL * L1 * sizeof(_Float16))

// ---------------------------------------------------------------------------
// Kernel 1: LDS-tiled transpose W_in [512, 81920] f32 -> WTh [81920, 512] f16.
// 64x64 tiles, float4 nontemporal global reads (W_in used once; keep L3 for
// WTh), 16 B fp16 stores (8 lanes x 16 B = 128 B contiguous per row segment).
// LDS pad-65: 65 % 32 == 1 -> both access phases are <=2-way aliased (free).
// ---------------------------------------------------------------------------
__global__ __launch_bounds__(256) void transpose_win(
    const float* __restrict__ W, _Float16* __restrict__ WTh)
{
    __shared__ float tile[64][65];
    const int jt = blockIdx.x * 64;           // input-feature tile base
    const int ot = blockIdx.y * 64;           // output-neuron tile base

    {
        const int tx = threadIdx.x & 15;      // float4 column
        const int ty = threadIdx.x >> 4;      // row
#pragma unroll
        for (int k = 0; k < 4; ++k) {
            const int o = ty + 16 * k;
            const v4f* p = (const v4f*)&W[(size_t)(ot + o) * IN_TOTAL + jt + 4 * tx];
            v4f v = __builtin_nontemporal_load(p);
            tile[4 * tx + 0][o] = v.x;
            tile[4 * tx + 1][o] = v.y;
            tile[4 * tx + 2][o] = v.z;
            tile[4 * tx + 3][o] = v.w;
        }
    }
    __syncthreads();
    {
        const int tx = threadIdx.x & 7;       // v8h column (8 fp16 = 16 B)
        const int ty = threadIdx.x >> 3;      // 0..31
#pragma unroll
        for (int k = 0; k < 2; ++k) {
            const int j = ty + 32 * k;
            v8f v;
#pragma unroll
            for (int c = 0; c < 8; ++c) v[c] = tile[j][8 * tx + c];
            v8h h = __builtin_convertvector(v, v8h);
            *(v8h*)&WTh[(size_t)(jt + j) * L1 + ot + 8 * tx] = h;
        }
    }
}

// ---------------------------------------------------------------------------
// Kernel 2: fused NNUE forward, one block per batch row, 512 threads.
//   Phase 1 (scan):   explicit 2-deep software pipeline — iteration i+1's two
//                     nontemporal loads are issued BEFORE iteration i's
//                     side-effecting push body, so HBM latency hides under the
//                     branchy compaction code. Nonzero test is an integer OR
//                     (features are exactly 0x0 / 0x3F800000).
//   Phase 2 (gather): 8 waves x 64 lanes; one feature = 512 fp16 = 1 KB =
//                     ONE wave64 x 16 B coalesced load. Branchless masked
//                     2-deep pipeline: uniform trip count, OOB features read
//                     sidx[0] (valid address) with scale 0 — every L3 load
//                     pair is in flight while the previous pair accumulates.
//   Phase 3-5: tiny dense layers, shuffle reductions, no atomics.
// Scan (HBM-BW-bound) and gather (L3-latency-bound) overlap across blocks.
// ---------------------------------------------------------------------------
__global__ __launch_bounds__(512) void nnue_fused(
    const float* __restrict__ wf, const float* __restrict__ bfeat,
    const _Float16* __restrict__ WTh,
    const float* __restrict__ b_in,
    const float* __restrict__ W1, const float* __restrict__ b1,
    const float* __restrict__ W2, const float* __restrict__ b2,
    const float* __restrict__ W3, const float* __restrict__ b3,
    float* __restrict__ out)
{
    const int b = blockIdx.x;
    const int t = threadIdx.x;

    __shared__ int   sidx[MAXIDX];
    __shared__ int   scnt;
    __shared__ float accs[8 * 64 * 9];   // [wave][lane][8 neurons + pad]
    __shared__ float l1s[L1];
    __shared__ float l2acc[L2];
    __shared__ float l2s[L2];
    __shared__ float l3s[L3_];

    if (t == 0) { scnt = 0; sidx[0] = 0; }   // sidx[0] init: safe OOB target
    __syncthreads();

    // ---- Phase 1: pipelined scan of both perspective rows
    const v4u* wrow = (const v4u*)(wf    + (size_t)b * IN_PER_SIDE);
    const v4u* brow = (const v4u*)(bfeat + (size_t)b * IN_PER_SIDE);
    const int nvec = IN_PER_SIDE / 4;  // 10240 -> exactly 20 iters @ stride 512

    v4u vw = __builtin_nontemporal_load(wrow + t);
    v4u vb = __builtin_nontemporal_load(brow + t);
    for (int i = t; ; ) {
        const int inext = i + 512;
        const bool more = inext < nvec;       // uniform across block
        v4u nw, nb;
        if (more) {
            nw = __builtin_nontemporal_load(wrow + inext);
            nb = __builtin_nontemporal_load(brow + inext);
        }
        if (vw.x | vw.y | vw.z | vw.w) {
            if (vw.x) sidx[atomicAdd(&scnt, 1)] = 4 * i + 0;
            if (vw.y) sidx[atomicAdd(&scnt, 1)] = 4 * i + 1;
            if (vw.z) sidx[atomicAdd(&scnt, 1)] = 4 * i + 2;
            if (vw.w) sidx[atomicAdd(&scnt, 1)] = 4 * i + 3;
        }
        if (vb.x | vb.y | vb.z | vb.w) {
            if (vb.x) sidx[atomicAdd(&scnt, 1)] = IN_PER_SIDE + 4 * i + 0;
            if (vb.y) sidx[atomicAdd(&scnt, 1)] = IN_PER_SIDE + 4 * i + 1;
            if (vb.z) sidx[atomicAdd(&scnt, 1)] = IN_PER_SIDE + 4 * i + 2;
            if (vb.w) sidx[atomicAdd(&scnt, 1)] = IN_PER_SIDE + 4 * i + 3;
        }
        if (!more) break;
        i = inext; vw = nw; vb = nb;
    }
    __syncthreads();

    // ---- Phase 2: gather active WTh columns; wave w, lane l.
    const int n = scnt;
    const int w = t >> 6;          // wave 0..7
    const int l = t & 63;          // lane 0..63
    const v8h* WTH8 = (const v8h*)WTh;   // feature f -> WTH8[f*64 + l]

    v8f acc0 = {0, 0, 0, 0, 0, 0, 0, 0};
    v8f acc1 = {0, 0, 0, 0, 0, 0, 0, 0};
    const int J     = (n + 7) >> 3;        // masked per-wave trip count
    const int Jeven = (J + 1) & ~1;        // round up to pair granularity

    // Prologue: load pair j=(0,1); masked slots read sidx[0] with scale 0.
    {
        const int f0 = w, f1 = w + 8;
        v8h h0 = WTH8[(size_t)sidx[f0 < n ? f0 : 0] * 64 + l];
        float s0 = (f0 < n) ? 1.0f : 0.0f;
        v8h h1 = WTH8[(size_t)sidx[f1 < n ? f1 : 0] * 64 + l];
        float s1 = (f1 < n) ? 1.0f : 0.0f;
        for (int j = 2; j < Jeven; j += 2) {
            const int g0 = w + 8 * j, g1 = g0 + 8;
            v8h p0 = WTH8[(size_t)sidx[g0 < n ? g0 : 0] * 64 + l];
            const float u0 = (g0 < n) ? 1.0f : 0.0f;
            v8h p1 = WTH8[(size_t)sidx[g1 < n ? g1 : 0] * 64 + l];
            const float u1 = (g1 < n) ? 1.0f : 0.0f;
            acc0 += s0 * __builtin_convertvector(h0, v8f);
            acc1 += s1 * __builtin_convertvector(h1, v8f);
            h0 = p0; s0 = u0; h1 = p1; s1 = u1;
        }
        acc0 += s0 * __builtin_convertvector(h0, v8f);
        acc1 += s1 * __builtin_convertvector(h1, v8f);
    }
    acc0 += acc1;

    // scalar LDS stores at pad-9 stride: bank = (9*l + i) % 32, 9 odd ->
    // distinct over 32 lanes per i -> conflict-free.
    {
        float* dst = &accs[(w * 64 + l) * 9];
#pragma unroll
        for (int i = 0; i < 8; ++i) dst[i] = acc0[i];
    }
    __syncthreads();

    // ---- reduce waves + bias + clipped ReLU; thread t = neuron t.
    {
        const int ll = t >> 3, c = t & 7;
        float s = 0.0f;
#pragma unroll
        for (int ww = 0; ww < 8; ++ww) s += accs[(ww * 64 + ll) * 9 + c];
        l1s[t] = fminf(fmaxf(s + b_in[t], 0.0f), 1.0f);
    }
    __syncthreads();

    // ---- Phase 3: l2 = clip(l1 @ W1.T + b1): output k owned by 16 lanes
    {
        const int kk = t >> 4;
        const int gg = t & 15;
        const float* wp = W1 + (size_t)kk * L1;
        float p = 0.0f;
        for (int o = gg; o < L1; o += 16) p += wp[o] * l1s[o];
#pragma unroll
        for (int off = 8; off > 0; off >>= 1) p += __shfl_down(p, off, 16);
        if (gg == 0) l2acc[kk] = p;
    }
    __syncthreads();
    if (t < L2) l2s[t] = fminf(fmaxf(l2acc[t] + b1[t], 0.0f), 1.0f);
    __syncthreads();

    // ---- Phase 4: l3 = clip(l2 @ W2.T + b2), 32x32
    if (t < L3_) {
        const float* wp = W2 + (size_t)t * L2;
        float p = b2[t];
#pragma unroll
        for (int q = 0; q < L2; ++q) p += wp[q] * l2s[q];
        l3s[t] = fminf(fmaxf(p, 0.0f), 1.0f);
    }
    __syncthreads();

    // ---- Phase 5: out = l3 @ W3.T + b3
    if (t == 0) {
        float p = b3[0];
#pragma unroll
        for (int q = 0; q < L3_; ++q) p += W3[q] * l3s[q];
        out[b] = p;
    }
}

// ---------------------------------------------------------------------------
// Fallback (ws too small for WTh): fused kernel reading W_in columns
// directly. Correct but slow; not expected to run (ws ~2.5 GiB >> 84 MB).
// ---------------------------------------------------------------------------
__global__ __launch_bounds__(512) void nnue_fallback(
    const float* __restrict__ wf, const float* __restrict__ bfeat,
    const float* __restrict__ W_in, const float* __restrict__ b_in,
    const float* __restrict__ W1, const float* __restrict__ b1,
    const float* __restrict__ W2, const float* __restrict__ b2,
    const float* __restrict__ W3, const float* __restrict__ b3,
    float* __restrict__ out)
{
    const int b = blockIdx.x;
    const int t = threadIdx.x;
    __shared__ int   idxs[MAXIDX];
    __shared__ int   scnt;
    __shared__ float l1s[L1];
    __shared__ float l2acc[L2];
    __shared__ float l2s[L2];
    __shared__ float l3s[L3_];

    if (t == 0) scnt = 0;
    __syncthreads();
    const v4f* wrow = (const v4f*)(wf    + (size_t)b * IN_PER_SIDE);
    const v4f* brow = (const v4f*)(bfeat + (size_t)b * IN_PER_SIDE);
    for (int i = t; i < IN_PER_SIDE / 4; i += 512) {
        v4f v = wrow[i];
        if (v.x != 0.0f) idxs[atomicAdd(&scnt, 1)] = 4 * i + 0;
        if (v.y != 0.0f) idxs[atomicAdd(&scnt, 1)] = 4 * i + 1;
        if (v.z != 0.0f) idxs[atomicAdd(&scnt, 1)] = 4 * i + 2;
        if (v.w != 0.0f) idxs[atomicAdd(&scnt, 1)] = 4 * i + 3;
        v4f u = brow[i];
        if (u.x != 0.0f) idxs[atomicAdd(&scnt, 1)] = IN_PER_SIDE + 4 * i + 0;
        if (u.y != 0.0f) idxs[atomicAdd(&scnt, 1)] = IN_PER_SIDE + 4 * i + 1;
        if (u.z != 0.0f) idxs[atomicAdd(&scnt, 1)] = IN_PER_SIDE + 4 * i + 2;
        if (u.w != 0.0f) idxs[atomicAdd(&scnt, 1)] = IN_PER_SIDE + 4 * i + 3;
    }
    __syncthreads();
    const int n = scnt;
    float a0 = 0.0f;
    const float* row = W_in + (size_t)t * IN_TOTAL;
    for (int i = 0; i < n; ++i) a0 += row[idxs[i]];
    l1s[t] = fminf(fmaxf(b_in[t] + a0, 0.0f), 1.0f);
    __syncthreads();
    {
        const int k = t >> 4, g = t & 15;
        const float* wp = W1 + (size_t)k * L1;
        float p = 0.0f;
        for (int o = g; o < L1; o += 16) p += wp[o] * l1s[o];
#pragma unroll
        for (int off = 8; off > 0; off >>= 1) p += __shfl_down(p, off, 16);
        if (g == 0) l2acc[k] = p;
    }
    __syncthreads();
    if (t < L2) l2s[t] = fminf(fmaxf(l2acc[t] + b1[t], 0.0f), 1.0f);
    __syncthreads();
    if (t < L3_) {
        const float* wp = W2 + (size_t)t * L2;
        float p = b2[t];
#pragma unroll
        for (int q = 0; q < L2; ++q) p += wp[q] * l2s[q];
        l3s[t] = fminf(fmaxf(p, 0.0f), 1.0f);
    }
    __syncthreads();
    if (t == 0) {
        float p = b3[0];
#pragma unroll
        for (int q = 0; q < L3_; ++q) p += W3[q] * l3s[q];
        out[b] = p;
    }
}

extern "C" void kernel_launch(void* const* d_in, const int* in_sizes, int n_in,
                              void* d_out, int out_size, void* d_ws, size_t ws_size,
                              hipStream_t stream) {
    const float* wf   = (const float*)d_in[0];
    const float* bfeat= (const float*)d_in[1];
    const float* W_in = (const float*)d_in[2];
    const float* b_in = (const float*)d_in[3];
    const float* W1   = (const float*)d_in[4];
    const float* b1   = (const float*)d_in[5];
    const float* W2   = (const float*)d_in[6];
    const float* b2   = (const float*)d_in[7];
    const float* W3   = (const float*)d_in[8];
    const float* b3   = (const float*)d_in[9];
    float* out = (float*)d_out;

    if (ws_size >= WT_BYTES) {
        _Float16* WTh = (_Float16*)d_ws;
        dim3 grid(IN_TOTAL / 64, L1 / 64);   // (1280, 8)
        transpose_win<<<grid, 256, 0, stream>>>(W_in, WTh);
        nnue_fused<<<BATCH, 512, 0, stream>>>(
            wf, bfeat, WTh, b_in, W1, b1, W2, b2, W3, b3, out);
    } else {
        nnue_fallback<<<BATCH, 512, 0, stream>>>(
            wf, bfeat, W_in, b_in, W1, b1, W2, b2, W3, b3, out);
    }
}